// Round 12
// baseline (408.545 us; speedup 1.0000x reference)
//
#include <hip/hip_runtime.h>
#include <math.h>

#define SEQ 256
#define BATCH 512
#define IN_DIM 512
#define HID 512
#define NQ 32

typedef float v2f __attribute__((ext_vector_type(2)));

__device__ __forceinline__ float fast_rcp(float x) { return __builtin_amdgcn_rcpf(x); }

__device__ __forceinline__ float tanh_fast(float x) {
    // tanh(x) = sign(x) * (1 - e) / (1 + e),  e = exp(-2|x|)  (never overflows)
    float a = fabsf(x);
    float e = __expf(-2.0f * a);
    float r = (1.0f - e) * fast_rcp(1.0f + e);
    return copysignf(r, x);
}

// ---- DPP cross-lane helpers (constant ctrl/mask via templates) -------------
template <int CTRL>
__device__ __forceinline__ float dpp_add(float x) {
    int t = __builtin_amdgcn_update_dpp(0, __float_as_int(x), CTRL, 0xF, 0xF, false);
    return x + __int_as_float(t);
}
// Sum over each 16-lane row (xp_kernel).
__device__ __forceinline__ float reduce16_add(float x) {
    x = dpp_add<0xB1>(x);   // quad_perm [1,0,3,2] : xor1
    x = dpp_add<0x4E>(x);   // quad_perm [2,3,0,1] : xor2
    x = dpp_add<0x141>(x);  // row_half_mirror     : xor4 equivalent
    x = dpp_add<0x140>(x);  // row_mirror          : xor8 equivalent
    return x;
}
template <int CTRL, int ROW_MASK>
__device__ __forceinline__ float dpp_mul1(float x) {
    int t = __builtin_amdgcn_update_dpp(0x3f800000 /*1.0f*/, __float_as_int(x),
                                        CTRL, ROW_MASK, 0xF, false);
    return x * __int_as_float(t);
}
// Inclusive cumprod within each 32-lane half of the wave.
// bcast15 masked to odd rows (0xA) so lane31 can't leak into the upper half.
__device__ __forceinline__ float scan32_mul(float x) {
    x = dpp_mul1<0x111, 0xF>(x);  // row_shr:1
    x = dpp_mul1<0x112, 0xF>(x);  // row_shr:2
    x = dpp_mul1<0x114, 0xF>(x);  // row_shr:4
    x = dpp_mul1<0x118, 0xF>(x);  // row_shr:8
    x = dpp_mul1<0x142, 0xA>(x);  // row_bcast:15 into odd rows
    return x;
}

// Block barrier WITHOUT vmcnt drain (__syncthreads would wait on Phase C's
// fire-and-forget global stores). LDS visibility only: lgkmcnt(0)+s_barrier.
#define BLOCK_BARRIER_LDS() asm volatile("s_waitcnt lgkmcnt(0)\n\ts_barrier" ::: "memory")

// ---------------------------------------------------------------------------
// Phase 1: Xp[row][nq] = fc_b[nq] + sum_k inputs[row][k] * fc_w[nq][k]
// Unchanged from rounds 6-11 (measured ~61 us).
// ---------------------------------------------------------------------------
__global__ __launch_bounds__(256, 4) void xp_kernel(const float* __restrict__ x,
                                                    const float* __restrict__ fc_w,
                                                    const float* __restrict__ fc_b,
                                                    float* __restrict__ xp) {
    const int tid = threadIdx.x;
    const int g2 = tid >> 4;  // 0..15 : owns nq {2g2, 2g2+1}
    const int s  = tid & 15;  // k lane: k = 4s + 64j

    __shared__ float4 tile4[16 * 128];  // 16 rows x 512 floats = 32 KB

    v2f wA_lo[8], wA_hi[8], wB_lo[8], wB_hi[8];
    {
        const float* wrA = fc_w + (size_t)(g2 * 2 + 0) * (IN_DIM + HID) + 4 * s;
        const float* wrB = fc_w + (size_t)(g2 * 2 + 1) * (IN_DIM + HID) + 4 * s;
#pragma unroll
        for (int j = 0; j < 8; ++j) {
            float4 a = *reinterpret_cast<const float4*>(wrA + 64 * j);
            float4 b = *reinterpret_cast<const float4*>(wrB + 64 * j);
            wA_lo[j] = (v2f){a.x, a.y}; wA_hi[j] = (v2f){a.z, a.w};
            wB_lo[j] = (v2f){b.x, b.y}; wB_hi[j] = (v2f){b.z, b.w};
        }
    }
    const float2 bias2 = reinterpret_cast<const float2*>(fc_b)[g2];

    const float4* x4 = reinterpret_cast<const float4*>(x) + (size_t)blockIdx.x * (16 * 128);
#pragma unroll
    for (int q = 0; q < 8; ++q)
        tile4[tid + 256 * q] = x4[tid + 256 * q];
    __syncthreads();

    const int row0 = blockIdx.x * 16;
    float2* xp2 = reinterpret_cast<float2*>(xp);
    for (int rp = 0; rp < 8; ++rp) {
        const int r0 = 2 * rp, r1 = 2 * rp + 1;
        v2f aA0 = (v2f){0.f, 0.f}, aA1 = aA0, aB0 = aA0, aB1 = aA0;
        v2f bA0 = aA0, bA1 = aA0, bB0 = aA0, bB1 = aA0;  // j-parity split (ILP)
#pragma unroll
        for (int j = 0; j < 8; j += 2) {
            float4 h0 = tile4[r0 * 128 + s + 16 * j];
            float4 h1 = tile4[r1 * 128 + s + 16 * j];
            v2f h0lo = (v2f){h0.x, h0.y}, h0hi = (v2f){h0.z, h0.w};
            v2f h1lo = (v2f){h1.x, h1.y}, h1hi = (v2f){h1.z, h1.w};
            aA0 = __builtin_elementwise_fma(h0lo, wA_lo[j], aA0);
            aA0 = __builtin_elementwise_fma(h0hi, wA_hi[j], aA0);
            aA1 = __builtin_elementwise_fma(h0lo, wB_lo[j], aA1);
            aA1 = __builtin_elementwise_fma(h0hi, wB_hi[j], aA1);
            aB0 = __builtin_elementwise_fma(h1lo, wA_lo[j], aB0);
            aB0 = __builtin_elementwise_fma(h1hi, wA_hi[j], aB0);
            aB1 = __builtin_elementwise_fma(h1lo, wB_lo[j], aB1);
            aB1 = __builtin_elementwise_fma(h1hi, wB_hi[j], aB1);
            float4 g0 = tile4[r0 * 128 + s + 16 * (j + 1)];
            float4 g1 = tile4[r1 * 128 + s + 16 * (j + 1)];
            v2f g0lo = (v2f){g0.x, g0.y}, g0hi = (v2f){g0.z, g0.w};
            v2f g1lo = (v2f){g1.x, g1.y}, g1hi = (v2f){g1.z, g1.w};
            bA0 = __builtin_elementwise_fma(g0lo, wA_lo[j + 1], bA0);
            bA0 = __builtin_elementwise_fma(g0hi, wA_hi[j + 1], bA0);
            bA1 = __builtin_elementwise_fma(g0lo, wB_lo[j + 1], bA1);
            bA1 = __builtin_elementwise_fma(g0hi, wB_hi[j + 1], bA1);
            bB0 = __builtin_elementwise_fma(g1lo, wA_lo[j + 1], bB0);
            bB0 = __builtin_elementwise_fma(g1hi, wA_hi[j + 1], bB0);
            bB1 = __builtin_elementwise_fma(g1lo, wB_lo[j + 1], bB1);
            bB1 = __builtin_elementwise_fma(g1hi, wB_hi[j + 1], bB1);
        }
        v2f sA0 = aA0 + bA0, sA1 = aA1 + bA1, sB0 = aB0 + bB0, sB1 = aB1 + bB1;
        float rA0 = reduce16_add(sA0.x + sA0.y);
        float rA1 = reduce16_add(sA1.x + sA1.y);
        float rB0 = reduce16_add(sB0.x + sB0.y);
        float rB1 = reduce16_add(sB1.x + sB1.y);
        if (s == 0) {
            xp2[(size_t)(row0 + r0) * 16 + g2] = make_float2(rA0 + bias2.x, rA1 + bias2.y);
            xp2[(size_t)(row0 + r1) * 16 + g2] = make_float2(rB0 + bias2.x, rB1 + bias2.y);
        }
    }
}

// ---------------------------------------------------------------------------
// Phase 2: per-batch recurrence at 4 WAVES/SIMD (the latency-hiding lever).
// Model from R8/R9/R10/R11 counters: step ~= VALU_issue/SIMD + residual,
// residual 2020cy @1 wave/SIMD, 1180cy @2 -> ~600-800 @4. R3's attempt at
// high occupancy died because __launch_bounds__ min-only let the compiler
// squeeze VGPR to 64 and spill; amdgpu_waves_per_eu(4,4) PINS the budget at
// 128. Per-thread state halved vs R8 so it fits without AGPR parking (the
// suspected source of R8's ~215 excess instrs/wave/step: VGPR=92 with ~128
// live floats -> accvgpr_read per use):
//   512 thr = 8 waves, wave w owns hid/k slice [64w, 64w+64); 1 hid row per
//   lane. wh = 32 floats, ow = 32 floats, temps ~50 -> ~115 VGPR.
//   A: grp=lane>>1 owns nq grp; sl=lane&1; k = 64w + 8j + 4sl + {0..3},
//      j=0..7: 8 b128 reads (2 distinct addrs/wave = free 2-way), 16 pk-FMA,
//      1 DPP xor1 reduce, b32 partial write.          [BLOCK_BARRIER_LDS]
//   B: qin = sum of 8 partials (b32 broadcast) + xps; cos + DPP cumprod;
//      lanes<32 sigmoid / >=32 tanh -> pwbuf[w][lane] (wave-private).
//   C: 16 uniform b128 reads (broadcast - cheap per R10 evidence), 32
//      pk-FMA, 1x state update + tanh, h write, 1 global store.
// One barrier/step, pbuf parity double-buffered, wave-private h edges.
// ---------------------------------------------------------------------------
__global__ __launch_bounds__(512)
__attribute__((amdgpu_waves_per_eu(4, 4)))
void rnn_kernel(const float* __restrict__ xp,
                const float* __restrict__ fc_w,
                const float* __restrict__ out_w,
                const float* __restrict__ out_b,
                float* __restrict__ out) {
    const int b = blockIdx.x;
    const int tid = threadIdx.x;    // 0..511
    const int w8 = tid >> 6;        // wave id 0..7 : owns hid/k [64w8, 64w8+64)
    const int lane = tid & 63;
    const int l31 = lane & 31;
    const int grp = lane >> 1;      // 0..31 : owns nq grp in Phase A
    const int sl = lane & 1;        // 2-way k split

    __shared__ __align__(16) float hbuf[HID];        // 2 KB, wave-private slices
    __shared__ __align__(16) float pbuf[2][8][NQ];   // 2 KB, qin partials
    __shared__ __align__(16) float pwbuf[8][64];     // 2 KB, sig[32]|tanh[32]
    __shared__ __align__(16) float xps[SEQ * NQ];    // 32 KB

    // Phase-A weights: k = 64*w8 + 8*j + 4*sl + {0..3}, j = 0..7  (32 floats)
    v2f wh_lo[8], wh_hi[8];
    {
        const float* wr = fc_w + (size_t)grp * (IN_DIM + HID) + IN_DIM + 64 * w8 + 4 * sl;
#pragma unroll
        for (int j = 0; j < 8; ++j) {
            float4 a = *reinterpret_cast<const float4*>(wr + 8 * j);
            wh_lo[j] = (v2f){a.x, a.y}; wh_hi[j] = (v2f){a.z, a.w};
        }
    }
    // Phase-C row: hid = 64*w8 + lane (one row, 32 floats as 16 v2f)
    const int hid = 64 * w8 + lane;
    v2f owv[16];
    {
        const float4* o = reinterpret_cast<const float4*>(out_w + (size_t)hid * NQ);
#pragma unroll
        for (int q4 = 0; q4 < 8; ++q4) {
            float4 a = o[q4];
            owv[2 * q4 + 0] = (v2f){a.x, a.y};
            owv[2 * q4 + 1] = (v2f){a.z, a.w};
        }
    }
    const float ob = out_b[hid];

    // stage xp[:, b, :] -> LDS once (2048 float4s / 512 threads = 4 each)
    {
        const float4* xpg = reinterpret_cast<const float4*>(xp);
        float4* xps4 = reinterpret_cast<float4*>(xps);
#pragma unroll
        for (int k = 0; k < 4; ++k) {
            int idx = tid + 512 * k;          // 0..2047
            int t = idx >> 3, q4 = idx & 7;
            xps4[idx] = xpg[((size_t)t * BATCH + b) * 8 + q4];
        }
    }
    hbuf[tid] = 0.0f;
    float c = 0.0f;
    __syncthreads();   // once, outside the loop (init visibility)

    float* hx_out = out + (size_t)SEQ * BATCH * HID + (size_t)b * HID;
    float* cx_out = hx_out + (size_t)BATCH * HID;

    // h float4 base for Phase A: float4 idx = 16*w8 + 2*j + sl
    const float4* h4s = reinterpret_cast<const float4*>(hbuf) + (16 * w8 + sl);

    int par = 0;
    for (int t = 0; t < SEQ; ++t) {
        // ---- Phase A: partial q_in over the wave's own 64-k slice ---------
        v2f aA = (v2f){0.f, 0.f}, bA = aA;   // j-parity ILP
#pragma unroll
        for (int j = 0; j < 8; j += 2) {
            float4 hv = h4s[2 * j];
            aA = __builtin_elementwise_fma((v2f){hv.x, hv.y}, wh_lo[j], aA);
            aA = __builtin_elementwise_fma((v2f){hv.z, hv.w}, wh_hi[j], aA);
            float4 gv = h4s[2 * (j + 1)];
            bA = __builtin_elementwise_fma((v2f){gv.x, gv.y}, wh_lo[j + 1], bA);
            bA = __builtin_elementwise_fma((v2f){gv.z, gv.w}, wh_hi[j + 1], bA);
        }
        v2f sA = aA + bA;
        float r = dpp_add<0xB1>(sA.x + sA.y);   // xor1: sum the sl pair
        if (sl == 0) pbuf[par][w8][grp] = r;

        BLOCK_BARRIER_LDS();                 // the ONE barrier per step

        // ---- Phase B: combine 8 partials + scan + activations -------------
        {
            const float* pb = &pbuf[par][0][0];
            float q01 = pb[l31] + pb[32 + l31];
            float q23 = pb[64 + l31] + pb[96 + l31];
            float q45 = pb[128 + l31] + pb[160 + l31];
            float q67 = pb[192 + l31] + pb[224 + l31];
            float qin = ((q01 + q23) + (q45 + q67)) + xps[t * NQ + l31];
            float pp = scan32_mul(__cosf(qin));       // cumprod of cosines
            float arg = (lane < 32) ? -pp : (-2.0f * pp);   // pp in [-1,1]
            float e = __expf(arg);
            float num = (lane < 32) ? 1.0f : (1.0f - e);
            float val = num * fast_rcp(1.0f + e);     // sigmoid | tanh
            pwbuf[w8][lane] = val;  // sig at [0..31], tanh at [32..63]
        }
        // (no fence: pwbuf is wave-private; DS ops are in-order per wave;
        //  compiler inserts lgkmcnt before first USE of the reads below)

        // ---- Phase C: f/g via q-pair pk-FMA + state update ----------------
        const float4* sb4 = reinterpret_cast<const float4*>(&pwbuf[w8][0]);   // sig
        const float4* tb4 = sb4 + 8;                                          // tanh
        v2f fa = (v2f){0.f, 0.f}, fb = fa, ga = fa, gb = fa;
#pragma unroll
        for (int m = 0; m < 8; ++m) {
            float4 sv = sb4[m];               // sig[4m .. 4m+3]
            float4 tv = tb4[m];               // tanh[4m .. 4m+3]
            fa = __builtin_elementwise_fma((v2f){sv.x, sv.y}, owv[2 * m + 0], fa);
            fb = __builtin_elementwise_fma((v2f){sv.z, sv.w}, owv[2 * m + 1], fb);
            ga = __builtin_elementwise_fma((v2f){tv.x, tv.y}, owv[2 * m + 0], ga);
            gb = __builtin_elementwise_fma((v2f){tv.z, tv.w}, owv[2 * m + 1], gb);
        }
        v2f sf = fa + fb, sg = ga + gb;
        float f = ob + sf.x + sf.y;
        float g = ob + sg.x + sg.y;
        c = f * (c + g);                     // f*c + i*g with i == f
        float h = f * tanh_fast(c);          // o == f

        hbuf[hid] = h;                       // wave-private slice
        out[((size_t)t * BATCH + b) * HID + hid] = h;
        if (t == SEQ - 1) {
            hx_out[hid] = h;
            cx_out[hid] = c;
        }
        // (no fence: next Phase A reads only this wave's hbuf slice)
        par ^= 1;
    }
}

extern "C" void kernel_launch(void* const* d_in, const int* in_sizes, int n_in,
                              void* d_out, int out_size, void* d_ws, size_t ws_size,
                              hipStream_t stream) {
    const float* inputs = (const float*)d_in[0];
    const float* fc_w   = (const float*)d_in[1];
    const float* fc_b   = (const float*)d_in[2];
    const float* out_w  = (const float*)d_in[3];
    const float* out_b  = (const float*)d_in[4];
    float* out = (float*)d_out;
    float* xp  = (float*)d_ws;   // SEQ*BATCH*NQ floats = 16.8 MB

    xp_kernel<<<(SEQ * BATCH) / 16, 256, 0, stream>>>(inputs, fc_w, fc_b, xp);
    rnn_kernel<<<BATCH, 512, 0, stream>>>(xp, fc_w, out_w, out_b, out);
}

// Round 13
// 365.598 us; speedup vs baseline: 1.1175x; 1.1175x over previous
//
#include <hip/hip_runtime.h>
#include <math.h>

#define SEQ 256
#define BATCH 512
#define IN_DIM 512
#define HID 512
#define NQ 32

typedef float v2f __attribute__((ext_vector_type(2)));

__device__ __forceinline__ float fast_rcp(float x) { return __builtin_amdgcn_rcpf(x); }

__device__ __forceinline__ float tanh_fast(float x) {
    // tanh(x) = sign(x) * (1 - e) / (1 + e),  e = exp(-2|x|)  (never overflows)
    float a = fabsf(x);
    float e = __expf(-2.0f * a);
    float r = (1.0f - e) * fast_rcp(1.0f + e);
    return copysignf(r, x);
}

// ---- DPP cross-lane helpers (constant ctrl/mask via templates) -------------
template <int CTRL>
__device__ __forceinline__ float dpp_add(float x) {
    int t = __builtin_amdgcn_update_dpp(0, __float_as_int(x), CTRL, 0xF, 0xF, false);
    return x + __int_as_float(t);
}
// Sum over each 16-lane row (xp_kernel).
__device__ __forceinline__ float reduce16_add(float x) {
    x = dpp_add<0xB1>(x);   // quad_perm [1,0,3,2] : xor1
    x = dpp_add<0x4E>(x);   // quad_perm [2,3,0,1] : xor2
    x = dpp_add<0x141>(x);  // row_half_mirror     : xor4 equivalent
    x = dpp_add<0x140>(x);  // row_mirror          : xor8 equivalent
    return x;
}
// Sum over each 4-lane quad (rnn Phase A).
__device__ __forceinline__ float reduce4_add(float x) {
    x = dpp_add<0xB1>(x);   // xor1
    x = dpp_add<0x4E>(x);   // xor2
    return x;
}
template <int CTRL, int ROW_MASK>
__device__ __forceinline__ float dpp_mul1(float x) {
    int t = __builtin_amdgcn_update_dpp(0x3f800000 /*1.0f*/, __float_as_int(x),
                                        CTRL, ROW_MASK, 0xF, false);
    return x * __int_as_float(t);
}
// Inclusive cumprod within each 32-lane half of the wave.
// bcast15 masked to odd rows (0xA) so lane31 can't leak into the upper half.
__device__ __forceinline__ float scan32_mul(float x) {
    x = dpp_mul1<0x111, 0xF>(x);  // row_shr:1
    x = dpp_mul1<0x112, 0xF>(x);  // row_shr:2
    x = dpp_mul1<0x114, 0xF>(x);  // row_shr:4
    x = dpp_mul1<0x118, 0xF>(x);  // row_shr:8
    x = dpp_mul1<0x142, 0xA>(x);  // row_bcast:15 into odd rows
    return x;
}

// Block barrier WITHOUT vmcnt drain (__syncthreads would wait on Phase C's
// fire-and-forget global stores). LDS visibility only: lgkmcnt(0)+s_barrier.
#define BLOCK_BARRIER_LDS() asm volatile("s_waitcnt lgkmcnt(0)\n\ts_barrier" ::: "memory")

// Empty asm that forces 8 v2f values to be materialized in arch VGPRs at this
// program point. Emits NO instructions; placed inside the t-loop it makes
// keeping the weights permanently register-resident the allocator's cheapest
// option -- defeating the remat-from-L2 / AGPR-parking behavior seen in
// R4-R12 (VGPR_Count 52-116 while ~128+ floats of weights are live).
#define PIN8(a)                                                               \
    asm volatile("" : "+v"(a[0]), "+v"(a[1]), "+v"(a[2]), "+v"(a[3]),         \
                      "+v"(a[4]), "+v"(a[5]), "+v"(a[6]), "+v"(a[7]))

// ---------------------------------------------------------------------------
// Phase 1: Xp[row][nq] = fc_b[nq] + sum_k inputs[row][k] * fc_w[nq][k]
// Unchanged from rounds 6-12 (measured ~61 us; reads 268 MB at ~70% of HBM
// achievable -- near its own floor).
// ---------------------------------------------------------------------------
__global__ __launch_bounds__(256, 4) void xp_kernel(const float* __restrict__ x,
                                                    const float* __restrict__ fc_w,
                                                    const float* __restrict__ fc_b,
                                                    float* __restrict__ xp) {
    const int tid = threadIdx.x;
    const int g2 = tid >> 4;  // 0..15 : owns nq {2g2, 2g2+1}
    const int s  = tid & 15;  // k lane: k = 4s + 64j

    __shared__ float4 tile4[16 * 128];  // 16 rows x 512 floats = 32 KB

    v2f wA_lo[8], wA_hi[8], wB_lo[8], wB_hi[8];
    {
        const float* wrA = fc_w + (size_t)(g2 * 2 + 0) * (IN_DIM + HID) + 4 * s;
        const float* wrB = fc_w + (size_t)(g2 * 2 + 1) * (IN_DIM + HID) + 4 * s;
#pragma unroll
        for (int j = 0; j < 8; ++j) {
            float4 a = *reinterpret_cast<const float4*>(wrA + 64 * j);
            float4 b = *reinterpret_cast<const float4*>(wrB + 64 * j);
            wA_lo[j] = (v2f){a.x, a.y}; wA_hi[j] = (v2f){a.z, a.w};
            wB_lo[j] = (v2f){b.x, b.y}; wB_hi[j] = (v2f){b.z, b.w};
        }
    }
    const float2 bias2 = reinterpret_cast<const float2*>(fc_b)[g2];

    const float4* x4 = reinterpret_cast<const float4*>(x) + (size_t)blockIdx.x * (16 * 128);
#pragma unroll
    for (int q = 0; q < 8; ++q)
        tile4[tid + 256 * q] = x4[tid + 256 * q];
    __syncthreads();

    const int row0 = blockIdx.x * 16;
    float2* xp2 = reinterpret_cast<float2*>(xp);
    for (int rp = 0; rp < 8; ++rp) {
        const int r0 = 2 * rp, r1 = 2 * rp + 1;
        v2f aA0 = (v2f){0.f, 0.f}, aA1 = aA0, aB0 = aA0, aB1 = aA0;
        v2f bA0 = aA0, bA1 = aA0, bB0 = aA0, bB1 = aA0;  // j-parity split (ILP)
#pragma unroll
        for (int j = 0; j < 8; j += 2) {
            float4 h0 = tile4[r0 * 128 + s + 16 * j];
            float4 h1 = tile4[r1 * 128 + s + 16 * j];
            v2f h0lo = (v2f){h0.x, h0.y}, h0hi = (v2f){h0.z, h0.w};
            v2f h1lo = (v2f){h1.x, h1.y}, h1hi = (v2f){h1.z, h1.w};
            aA0 = __builtin_elementwise_fma(h0lo, wA_lo[j], aA0);
            aA0 = __builtin_elementwise_fma(h0hi, wA_hi[j], aA0);
            aA1 = __builtin_elementwise_fma(h0lo, wB_lo[j], aA1);
            aA1 = __builtin_elementwise_fma(h0hi, wB_hi[j], aA1);
            aB0 = __builtin_elementwise_fma(h1lo, wA_lo[j], aB0);
            aB0 = __builtin_elementwise_fma(h1hi, wA_hi[j], aB0);
            aB1 = __builtin_elementwise_fma(h1lo, wB_lo[j], aB1);
            aB1 = __builtin_elementwise_fma(h1hi, wB_hi[j], aB1);
            float4 g0 = tile4[r0 * 128 + s + 16 * (j + 1)];
            float4 g1 = tile4[r1 * 128 + s + 16 * (j + 1)];
            v2f g0lo = (v2f){g0.x, g0.y}, g0hi = (v2f){g0.z, g0.w};
            v2f g1lo = (v2f){g1.x, g1.y}, g1hi = (v2f){g1.z, g1.w};
            bA0 = __builtin_elementwise_fma(g0lo, wA_lo[j + 1], bA0);
            bA0 = __builtin_elementwise_fma(g0hi, wA_hi[j + 1], bA0);
            bA1 = __builtin_elementwise_fma(g0lo, wB_lo[j + 1], bA1);
            bA1 = __builtin_elementwise_fma(g0hi, wB_hi[j + 1], bA1);
            bB0 = __builtin_elementwise_fma(g1lo, wA_lo[j + 1], bB0);
            bB0 = __builtin_elementwise_fma(g1hi, wA_hi[j + 1], bB0);
            bB1 = __builtin_elementwise_fma(g1lo, wB_lo[j + 1], bB1);
            bB1 = __builtin_elementwise_fma(g1hi, wB_hi[j + 1], bB1);
        }
        v2f sA0 = aA0 + bA0, sA1 = aA1 + bA1, sB0 = aB0 + bB0, sB1 = aB1 + bB1;
        float rA0 = reduce16_add(sA0.x + sA0.y);
        float rA1 = reduce16_add(sA1.x + sA1.y);
        float rB0 = reduce16_add(sB0.x + sB0.y);
        float rB1 = reduce16_add(sB1.x + sB1.y);
        if (s == 0) {
            xp2[(size_t)(row0 + r0) * 16 + g2] = make_float2(rA0 + bias2.x, rA1 + bias2.y);
            xp2[(size_t)(row0 + r1) * 16 + g2] = make_float2(rB0 + bias2.x, rB1 + bias2.y);
        }
    }
}

// ---------------------------------------------------------------------------
// Phase 2: EXACT round-8 structure (best known: 303 us) + weight PINS.
// R4-R12 post-mortems converge on one story: the allocator never dedicates
// VGPRs to the ~128 loop-invariant weight floats (VGPR_Count 52-116 with no
// scratch traffic) -- it rematerializes them from L2 inside the t-loop /
// parks them in AGPRs, costing ~200+ excess instr-slots per wave per step
// and L2-latency stalls in the serial chain. PIN8 inside the loop forces
// arch-VGPR residency. Health check: VGPR_Count must jump to >= ~170.
// ---------------------------------------------------------------------------
__global__ __launch_bounds__(256)
__attribute__((amdgpu_waves_per_eu(2, 2)))
void rnn_kernel(const float* __restrict__ xp,
                const float* __restrict__ fc_w,
                const float* __restrict__ out_w,
                const float* __restrict__ out_b,
                float* __restrict__ out) {
    const int b = blockIdx.x;
    const int tid = threadIdx.x;
    const int w4 = tid >> 6;    // wave id 0..3 : owns hid [128w4, 128w4+128)
    const int lane = tid & 63;
    const int l31 = lane & 31;
    const int grp = lane >> 2;  // 0..15 : owns nq {2grp, 2grp+1} in Phase A
    const int sl = lane & 3;    // 4-way k split

    __shared__ __align__(16) float hbuf[HID];        // 2 KB, wave-private slices
    __shared__ __align__(16) float pbuf[2][4][NQ];   // 1 KB, qin partials
    __shared__ __align__(16) float pwbuf[4][64];     // 1 KB, sig[32]|tanh[32]
    __shared__ __align__(16) float xps[SEQ * NQ];    // 32 KB

    // Phase-A weights: k = 128*w4 + 16*j + 4*sl + {0..3}, j = 0..7
    v2f whA_lo[8], whA_hi[8], whB_lo[8], whB_hi[8];
    {
        const int kbase = IN_DIM + 128 * w4 + 4 * sl;
        const float* wrA = fc_w + (size_t)(grp * 2 + 0) * (IN_DIM + HID) + kbase;
        const float* wrB = fc_w + (size_t)(grp * 2 + 1) * (IN_DIM + HID) + kbase;
#pragma unroll
        for (int j = 0; j < 8; ++j) {
            float4 a = *reinterpret_cast<const float4*>(wrA + 16 * j);
            float4 c = *reinterpret_cast<const float4*>(wrB + 16 * j);
            whA_lo[j] = (v2f){a.x, a.y}; whA_hi[j] = (v2f){a.z, a.w};
            whB_lo[j] = (v2f){c.x, c.y}; whB_hi[j] = (v2f){c.z, c.w};
        }
    }
    // Phase-C rows as v2f pairs: hid0 = 128*w4 + lane, hid1 = hid0 + 64
    const int hid0 = 128 * w4 + lane;
    const int hid1 = hid0 + 64;
    v2f ow0v[16], ow1v[16];
    {
        const float4* o0 = reinterpret_cast<const float4*>(out_w + (size_t)hid0 * NQ);
        const float4* o1 = reinterpret_cast<const float4*>(out_w + (size_t)hid1 * NQ);
#pragma unroll
        for (int q4 = 0; q4 < 8; ++q4) {
            float4 a = o0[q4], bq = o1[q4];
            ow0v[2 * q4 + 0] = (v2f){a.x, a.y};
            ow0v[2 * q4 + 1] = (v2f){a.z, a.w};
            ow1v[2 * q4 + 0] = (v2f){bq.x, bq.y};
            ow1v[2 * q4 + 1] = (v2f){bq.z, bq.w};
        }
    }
    const float ob0 = out_b[hid0];
    const float ob1 = out_b[hid1];

    // stage xp[:, b, :] -> LDS once
    {
        const float4* xpg = reinterpret_cast<const float4*>(xp);
        float4* xps4 = reinterpret_cast<float4*>(xps);
#pragma unroll
        for (int k = 0; k < 8; ++k) {
            int idx = tid + 256 * k;          // 0..2047
            int t = idx >> 3, q4 = idx & 7;
            xps4[idx] = xpg[((size_t)t * BATCH + b) * 8 + q4];
        }
    }
    hbuf[tid] = 0.0f;
    hbuf[tid + 256] = 0.0f;
    float c0 = 0.0f, c1 = 0.0f;
    __syncthreads();   // once, outside the loop (init visibility)

    float* hx_out = out + (size_t)SEQ * BATCH * HID + (size_t)b * HID;
    float* cx_out = hx_out + (size_t)BATCH * HID;

    // h float4 base for Phase A: idx = 32*w4 + sl + 4*j  (static offsets 4j)
    const float4* h4s = reinterpret_cast<const float4*>(hbuf) + (32 * w4 + sl);

    int par = 0;
    for (int t = 0; t < SEQ; ++t) {
        // Force all weight arrays into arch VGPRs every iteration (no-op asm).
        PIN8(whA_lo); PIN8(whA_hi); PIN8(whB_lo); PIN8(whB_hi);
        PIN8(ow0v);   PIN8((&ow0v[8])); PIN8(ow1v); PIN8((&ow1v[8]));

        // ---- Phase A: partial q_in over the wave's own 128-k slice --------
        v2f aA = (v2f){0.f, 0.f}, aB = aA, bA = aA, bB = aA;  // j-parity ILP
#pragma unroll
        for (int j = 0; j < 8; j += 2) {
            float4 hv = h4s[4 * j];
            v2f hlo = (v2f){hv.x, hv.y}, hhi = (v2f){hv.z, hv.w};
            aA = __builtin_elementwise_fma(hlo, whA_lo[j], aA);
            aA = __builtin_elementwise_fma(hhi, whA_hi[j], aA);
            aB = __builtin_elementwise_fma(hlo, whB_lo[j], aB);
            aB = __builtin_elementwise_fma(hhi, whB_hi[j], aB);
            float4 gv = h4s[4 * (j + 1)];
            v2f glo = (v2f){gv.x, gv.y}, ghi = (v2f){gv.z, gv.w};
            bA = __builtin_elementwise_fma(glo, whA_lo[j + 1], bA);
            bA = __builtin_elementwise_fma(ghi, whA_hi[j + 1], bA);
            bB = __builtin_elementwise_fma(glo, whB_lo[j + 1], bB);
            bB = __builtin_elementwise_fma(ghi, whB_hi[j + 1], bB);
        }
        v2f sA = aA + bA, sB = aB + bB;
        float rA = reduce4_add(sA.x + sA.y);
        float rB = reduce4_add(sB.x + sB.y);
        if (sl == 0)
            *reinterpret_cast<float2*>(&pbuf[par][w4][2 * grp]) = make_float2(rA, rB);

        BLOCK_BARRIER_LDS();                 // the ONE barrier per step

        // ---- Phase B: combine partials + scan + activations ---------------
        {
            const float* pb = &pbuf[par][0][0];
            float qin = (pb[l31] + pb[32 + l31]) + (pb[64 + l31] + pb[96 + l31])
                      + xps[t * NQ + l31];
            float pp = scan32_mul(__cosf(qin));       // cumprod of cosines
            float arg = (lane < 32) ? -pp : (-2.0f * pp);   // pp in [-1,1]
            float e = __expf(arg);
            float num = (lane < 32) ? 1.0f : (1.0f - e);
            float val = num * fast_rcp(1.0f + e);     // sigmoid | tanh
            pwbuf[w4][lane] = val;  // sig at [0..31], tanh at [32..63]
        }
        // (no fence: pwbuf is wave-private; DS ops are in-order per wave;
        //  compiler inserts lgkmcnt before first USE of the reads below)

        // ---- Phase C: f/g via q-pair pk-FMA + state update ----------------
        const float4* sb4 = reinterpret_cast<const float4*>(&pwbuf[w4][0]);   // sig
        const float4* tb4 = sb4 + 8;                                          // tanh
        v2f f0a = (v2f){0.f, 0.f}, f0b = f0a, g0a = f0a, g0b = f0a;
        v2f f1a = f0a, f1b = f0a, g1a = f0a, g1b = f0a;
#pragma unroll
        for (int m = 0; m < 8; ++m) {
            float4 sv = sb4[m];               // sig[4m .. 4m+3]
            float4 tv = tb4[m];               // tanh[4m .. 4m+3]
            v2f slo = (v2f){sv.x, sv.y}, shi = (v2f){sv.z, sv.w};
            v2f tlo = (v2f){tv.x, tv.y}, thi = (v2f){tv.z, tv.w};
            f0a = __builtin_elementwise_fma(slo, ow0v[2 * m + 0], f0a);
            f0b = __builtin_elementwise_fma(shi, ow0v[2 * m + 1], f0b);
            g0a = __builtin_elementwise_fma(tlo, ow0v[2 * m + 0], g0a);
            g0b = __builtin_elementwise_fma(thi, ow0v[2 * m + 1], g0b);
            f1a = __builtin_elementwise_fma(slo, ow1v[2 * m + 0], f1a);
            f1b = __builtin_elementwise_fma(shi, ow1v[2 * m + 1], f1b);
            g1a = __builtin_elementwise_fma(tlo, ow1v[2 * m + 0], g1a);
            g1b = __builtin_elementwise_fma(thi, ow1v[2 * m + 1], g1b);
        }
        v2f sf0 = f0a + f0b, sg0 = g0a + g0b, sf1 = f1a + f1b, sg1 = g1a + g1b;
        float f0 = ob0 + sf0.x + sf0.y, g0 = ob0 + sg0.x + sg0.y;
        float f1 = ob1 + sf1.x + sf1.y, g1 = ob1 + sg1.x + sg1.y;
        c0 = f0 * (c0 + g0);                 // f*c + i*g with i == f
        c1 = f1 * (c1 + g1);
        float h0 = f0 * tanh_fast(c0);       // o == f
        float h1 = f1 * tanh_fast(c1);

        hbuf[hid0] = h0;                     // wave-private slice
        hbuf[hid1] = h1;
        float* orow = out + ((size_t)t * BATCH + b) * HID;
        orow[hid0] = h0;
        orow[hid1] = h1;
        if (t == SEQ - 1) {
            hx_out[hid0] = h0; hx_out[hid1] = h1;
            cx_out[hid0] = c0; cx_out[hid1] = c1;
        }
        // (no fence: next Phase A reads only this wave's hbuf slice)
        par ^= 1;
    }
}

extern "C" void kernel_launch(void* const* d_in, const int* in_sizes, int n_in,
                              void* d_out, int out_size, void* d_ws, size_t ws_size,
                              hipStream_t stream) {
    const float* inputs = (const float*)d_in[0];
    const float* fc_w   = (const float*)d_in[1];
    const float* fc_b   = (const float*)d_in[2];
    const float* out_w  = (const float*)d_in[3];
    const float* out_b  = (const float*)d_in[4];
    float* out = (float*)d_out;
    float* xp  = (float*)d_ws;   // SEQ*BATCH*NQ floats = 16.8 MB

    xp_kernel<<<(SEQ * BATCH) / 16, 256, 0, stream>>>(inputs, fc_w, fc_b, xp);
    rnn_kernel<<<BATCH, 256, 0, stream>>>(xp, fc_w, out_w, out_b, out);
}